// Round 5
// baseline (108.798 us; speedup 1.0000x reference)
//
#include <hip/hip_runtime.h>

#define HH 2048
#define WW 2048
#define NB 2
#define FEPS 5e-4f

// fused tile geometry
#define TX 64
#define TYW 4
#define VY 8
#define TILEH (TYW*VY)   // 32
#define SPH (TILEH+4)    // 36
#define SPW (TX+4)       // 68
#define SPP (SPW+1)      // 69 (pad)
#define SSH (TILEH+2)    // 34
#define SSW (TX+2)       // 66
#define SSP (SSW+1)      // 67 (pad)

__device__ __forceinline__ int refl(int i, int n) {
    if (i < 0) return -i;
    if (i >= n) return 2 * n - 2 - i;
    return i;
}

// BIT-IDENTICAL to round-4: f64 accumulation in this exact expression order.
__device__ __forceinline__ float gauss9_f64(float p00, float p01, float p02,
                                            float p10, float p11, float p12,
                                            float p20, float p21, float p22) {
    const double a = 0.0625 * ((double)p00 + (double)p02 + (double)p20 + (double)p22)
                   + 0.125  * ((double)p01 + (double)p10 + (double)p12 + (double)p21)
                   + 0.25   * (double)p11;
    return (float)a;
}

__global__ void init_norm_kernel(unsigned int* nb) {
    if (threadIdx.x < NB) nb[threadIdx.x] = 0u;
}

// One block per (row, image); 256 threads x 8 px. Vectorized row loads.
__global__ __launch_bounds__(256) void gauss_max_kernel(const float* __restrict__ pan,
                                                        unsigned int* __restrict__ norm_bits) {
    const int b = blockIdx.y;
    // XCD-swizzle rows: 8 contiguous 256-row stripes (2048 = 8*256, bijective)
    const int bid = blockIdx.x;
    const int i = (bid & 7) * 256 + (bid >> 3);
    const float* __restrict__ img = pan + (size_t)b * HH * WW;
    const int t = threadIdx.x;
    const int j0 = t * 8;
    const int im = refl(i - 1, HH), ip = refl(i + 1, HH);
    const float* __restrict__ r0 = img + (size_t)im * WW;
    const float* __restrict__ r1 = img + (size_t)i  * WW;
    const float* __restrict__ r2 = img + (size_t)ip * WW;

    float c0[10], c1[10], c2[10];   // cols j0-1 .. j0+8
    {
        const float4 B0 = *(const float4*)(r0 + j0);
        const float4 C0 = *(const float4*)(r0 + j0 + 4);
        const float4 B1 = *(const float4*)(r1 + j0);
        const float4 C1 = *(const float4*)(r1 + j0 + 4);
        const float4 B2 = *(const float4*)(r2 + j0);
        const float4 C2 = *(const float4*)(r2 + j0 + 4);
        c0[1]=B0.x; c0[2]=B0.y; c0[3]=B0.z; c0[4]=B0.w; c0[5]=C0.x; c0[6]=C0.y; c0[7]=C0.z; c0[8]=C0.w;
        c1[1]=B1.x; c1[2]=B1.y; c1[3]=B1.z; c1[4]=B1.w; c1[5]=C1.x; c1[6]=C1.y; c1[7]=C1.z; c1[8]=C1.w;
        c2[1]=B2.x; c2[2]=B2.y; c2[3]=B2.z; c2[4]=B2.w; c2[5]=C2.x; c2[6]=C2.y; c2[7]=C2.z; c2[8]=C2.w;
        if (t == 0) { c0[0] = B0.y; c1[0] = B1.y; c2[0] = B2.y; }          // refl(-1)=1
        else        { c0[0] = r0[j0-1]; c1[0] = r1[j0-1]; c2[0] = r2[j0-1]; }
        if (t == 255) { c0[9] = C0.z; c1[9] = C1.z; c2[9] = C2.z; }        // refl(2048)=2046
        else          { c0[9] = r0[j0+8]; c1[9] = r1[j0+8]; c2[9] = r2[j0+8]; }
    }

    float lmax = 0.0f;
    #pragma unroll
    for (int k = 0; k < 8; ++k) {
        const float g = gauss9_f64(c0[k], c0[k+1], c0[k+2],
                                   c1[k], c1[k+1], c1[k+2],
                                   c2[k], c2[k+1], c2[k+2]);
        lmax = fmaxf(lmax, g);
    }
    #pragma unroll
    for (int off = 32; off > 0; off >>= 1)
        lmax = fmaxf(lmax, __shfl_down(lmax, off, 64));
    __shared__ float smax[4];
    const int lane = threadIdx.x & 63, wid = threadIdx.x >> 6;
    if (lane == 0) smax[wid] = lmax;
    __syncthreads();
    if (threadIdx.x == 0) {
        const float m = fmaxf(fmaxf(smax[0], smax[1]), fmaxf(smax[2], smax[3]));
        atomicMax(norm_bits + b, __float_as_uint(m));
    }
}

__global__ __launch_bounds__(256) void fused_kernel(const float* __restrict__ pan,
                                                    const unsigned int* __restrict__ norm_bits,
                                                    float* __restrict__ out) {
    __shared__ float sp[SPH][SPP];
    __shared__ float ss[SSH][SSP];

    const int b  = blockIdx.z;
    const int bi = blockIdx.y * TILEH;
    const int bj = blockIdx.x * TX;
    const float* __restrict__ img = pan + (size_t)b * HH * WW;
    const int tx = threadIdx.x, ty = threadIdx.y;
    const int tid = ty * TX + tx;

    const float norm = __uint_as_float(norm_bits[b]);

    // Stage A: pan tile (rows bi-2..bi+33, cols bj-2..bj+65), reflect at load
    for (int idx = tid; idx < SPH * SPW; idx += 256) {
        const int r = idx / SPW, c = idx % SPW;
        sp[r][c] = img[refl(bi - 2 + r, HH) * WW + refl(bj - 2 + c, WW)];
    }
    __syncthreads();

    // Stage B: scaled pan_lp (identical chain to round-4)
    for (int idx = tid; idx < SSH * SSW; idx += 256) {
        const int r = idx / SSW, c = idx % SSW;
        const float g = gauss9_f64(sp[r][c],   sp[r][c+1],   sp[r][c+2],
                                   sp[r+1][c], sp[r+1][c+1], sp[r+1][c+2],
                                   sp[r+2][c], sp[r+2][c+1], sp[r+2][c+2]);
        ss[r][c] = __fdiv_rn(__fmul_rn(g, 255.0f), norm);
    }
    __syncthreads();

    const float scale = __fdiv_rn(norm, 255.0f);
    const int ri0 = ty * VY;
    const int j = bj + tx;

    // rolling 3x3 window: row0 = i-1, row1 = i, row2 = i+1
    float s00 = ss[ri0][tx],     s01 = ss[ri0][tx+1],     s02 = ss[ri0][tx+2];
    float s10 = ss[ri0+1][tx],   s11 = ss[ri0+1][tx+1],   s12 = ss[ri0+1][tx+2];
    float f00 = floorf(s00), f01 = floorf(s01), f02 = floorf(s02);
    float f10 = floorf(s10), f11 = floorf(s11), f12 = floorf(s12);
    float pprev = sp[ri0 + 1][tx + 2];

    const size_t plane = (size_t)HH * WW;

    #pragma unroll
    for (int rr = 0; rr < VY; ++rr) {
        const int ri = ri0 + rr;
        const int i  = bi + ri;
        const float s20 = ss[ri+2][tx], s21 = ss[ri+2][tx+1], s22 = ss[ri+2][tx+2];
        const float f20 = floorf(s20), f21 = floorf(s21), f22 = floorf(s22);
        const float pc = sp[ri + 2][tx + 2];

        // Sobel (identical f64 chain)
        const double sx64 = ((double)s20 + 2.0 * (double)s21 + (double)s22)
                          - ((double)s00 + 2.0 * (double)s01 + (double)s02);
        const double sy64 = ((double)s02 + 2.0 * (double)s12 + (double)s22)
                          - ((double)s00 + 2.0 * (double)s10 + (double)s20);
        const float ex = rintf(fminf(fabsf((float)sx64), 255.0f));
        const float ey = rintf(fminf(fabsf((float)sy64), 255.0f));
        const float sob = rintf(__fadd_rn(__fmul_rn(0.5f, ex), __fmul_rn(0.5f, ey)));

        // Prewitt / Roberts on floors (exact)
        const float px = (f00 + f01 + f02) - (f20 + f21 + f22);
        const float py = (f02 + f12 + f22) - (f00 + f10 + f20);
        const float epx = rintf(fminf(fabsf(px), 255.0f));
        const float epy = rintf(fminf(fabsf(py), 255.0f));
        const float prew = rintf(0.5f * epx + 0.5f * epy);

        const float rx = f11 - f00;
        const float ry = f10 - f01;
        const float erx = rintf(fminf(fabsf(rx), 255.0f));
        const float ery = rintf(fminf(fabsf(ry), 255.0f));
        const float rob = rintf(0.5f * erx + 0.5f * ery);

        // Hedged Laplace (identical logic to round-4)
        float el;
        {
            const float sm = s11;
            const float kM = rintf(sm);
            float m0; int um;
            if (fabsf(sm - kM) < FEPS) { m0 = kM - 1.0f; um = 1; }
            else                       { m0 = f11;       um = 0; }

            float S0 = 0.0f; int nu = 0;
            { const float v = s00; const float kk = rintf(v);
              if (fabsf(v - kk) < FEPS) { S0 += kk - 1.0f; ++nu; } else S0 += f00; }
            { const float v = s02; const float kk = rintf(v);
              if (fabsf(v - kk) < FEPS) { S0 += kk - 1.0f; ++nu; } else S0 += f02; }
            { const float v = s20; const float kk = rintf(v);
              if (fabsf(v - kk) < FEPS) { S0 += kk - 1.0f; ++nu; } else S0 += f20; }
            { const float v = s22; const float kk = rintf(v);
              if (fabsf(v - kk) < FEPS) { S0 += kk - 1.0f; ++nu; } else S0 += f22; }

            float Lmin = 1e30f, Lmax = -1e30f;
            for (int mm = 0; mm <= um; ++mm) {
                const float mval = m0 + (float)mm;
                for (int jj = 0; jj <= nu; ++jj) {
                    const float tt = 2.0f * (S0 + (float)jj) - 8.0f * mval;
                    const float L = rintf(fminf(fabsf(tt), 255.0f));
                    Lmin = fminf(Lmin, L);
                    Lmax = fmaxf(Lmax, L);
                }
            }
            el = 0.5f * (Lmin + Lmax);
        }

        // forward diffs (exact f32)
        float left = __shfl_up(pc, 1, 64);
        if (tx == 0) left = sp[ri + 2][1];
        const float dy = (i > 0) ? __fsub_rn(pc, pprev) : 0.0f;
        const float dx = (j > 0) ? __fsub_rn(pc, left) : 0.0f;

        const size_t base = ((size_t)(b * 6) * HH + i) * WW + j;
        out[base]             = dy;
        out[base + plane]     = dx;
        out[base + 2 * plane] = __fmul_rn(rob,  scale);
        out[base + 3 * plane] = __fmul_rn(prew, scale);
        out[base + 4 * plane] = __fmul_rn(sob,  scale);
        out[base + 5 * plane] = __fmul_rn(el,   scale);

        // roll
        s00 = s10; s01 = s11; s02 = s12;
        s10 = s20; s11 = s21; s12 = s22;
        f00 = f10; f01 = f11; f02 = f12;
        f10 = f20; f11 = f21; f12 = f22;
        pprev = pc;
    }
}

extern "C" void kernel_launch(void* const* d_in, const int* in_sizes, int n_in,
                              void* d_out, int out_size, void* d_ws, size_t ws_size,
                              hipStream_t stream) {
    const float* pan = (const float*)d_in[0];
    float* out = (float*)d_out;
    unsigned int* norm_bits = (unsigned int*)d_ws;

    hipLaunchKernelGGL(init_norm_kernel, dim3(1), dim3(64), 0, stream, norm_bits);
    hipLaunchKernelGGL(gauss_max_kernel, dim3(HH, NB), dim3(256), 0, stream, pan, norm_bits);
    dim3 grid(WW / TX, HH / TILEH, NB);
    dim3 block(TX, TYW);
    hipLaunchKernelGGL(fused_kernel, grid, block, 0, stream, pan, norm_bits, out);
}